// Round 9
// baseline (2560.621 us; speedup 1.0000x reference)
//
#include <hip/hip_runtime.h>

#define TT 512
#define BB 32
#define II 512
#define HH 1024
#define G3 3072
#define TBH (TT * BB * HH) /* 16777216 */

typedef __attribute__((ext_vector_type(8))) short short8;
typedef __attribute__((ext_vector_type(4))) float f32x4;

__device__ __forceinline__ float sigmoidf_(float x) {
    return 1.f / (1.f + __expf(-x));
}
__device__ __forceinline__ float tanh_fast(float x) {
    float e2 = __expf(2.f * x);
    return 1.f - 2.f / (e2 + 1.f);
}
/* round-to-nearest-even f32 -> bf16 (top 16 bits) */
__device__ __forceinline__ unsigned rne16(float x) {
    unsigned u = __float_as_uint(x);
    return (u + 0x7FFFu + ((u >> 16) & 1u)) >> 16;
}
/* split x = hi + lo (both bf16); |x - hi - lo| <= ~2^-18 |x|.
   For finite x, neither hi nor lo can be 0xFFFF (bf16 NaN) -> sentinel-safe. */
__device__ __forceinline__ void bsplit(float x, unsigned& hi, unsigned& lo) {
    unsigned h16 = rne16(x);
    float xh = __uint_as_float(h16 << 16);
    hi = h16;
    lo = rne16(x - xh); /* x - xh is exact */
}

/* ---- pre-split x (M x 512 f32) -> packed bf16 hi/lo pair planes ----
   pair u32 = bf16(k even) | bf16(k odd)<<16 ; plane layout [row][k/2]. */
__global__ __launch_bounds__(256) void k_split_x(const float* __restrict__ x,
                                                 unsigned* __restrict__ xh,
                                                 unsigned* __restrict__ xl) {
    int g = blockIdx.x * 256 + threadIdx.x; /* 1,048,576 threads x 8 elems */
    const float4* src = (const float4*)(x + (size_t)g * 8);
    float4 a = src[0], b = src[1];
    unsigned h[8], l[8];
    bsplit(a.x, h[0], l[0]); bsplit(a.y, h[1], l[1]);
    bsplit(a.z, h[2], l[2]); bsplit(a.w, h[3], l[3]);
    bsplit(b.x, h[4], l[4]); bsplit(b.y, h[5], l[5]);
    bsplit(b.z, h[6], l[6]); bsplit(b.w, h[7], l[7]);
    uint4 ph = {h[0] | (h[1] << 16), h[2] | (h[3] << 16),
                h[4] | (h[5] << 16), h[6] | (h[7] << 16)};
    uint4 pl = {l[0] | (l[1] << 16), l[2] | (l[3] << 16),
                l[4] | (l[5] << 16), l[6] | (l[7] << 16)};
    *(uint4*)(xh + (size_t)g * 4) = ph;
    *(uint4*)(xl + (size_t)g * 4) = pl;
}

/* ---- pre-split + transpose w_ih (512 x 3072) -> wt planes [n 3072][k/2 256] */
__global__ __launch_bounds__(256) void k_split_w(const float* __restrict__ w,
                                                 unsigned* __restrict__ wth,
                                                 unsigned* __restrict__ wtl) {
    int g = blockIdx.x * 256 + threadIdx.x; /* 196,608 = 3072 n x 64 kb */
    int n = g % G3, kb = g / G3;
    int k0 = kb * 8;
    unsigned h[8], l[8];
#pragma unroll
    for (int j = 0; j < 8; ++j) /* reads coalesced across lanes (n contig) */
        bsplit(w[(size_t)(k0 + j) * G3 + n], h[j], l[j]);
    uint4 ph = {h[0] | (h[1] << 16), h[2] | (h[3] << 16),
                h[4] | (h[5] << 16), h[6] | (h[7] << 16)};
    uint4 pl = {l[0] | (l[1] << 16), l[2] | (l[3] << 16),
                l[4] | (l[5] << 16), l[6] | (l[7] << 16)};
    *(uint4*)(wth + (size_t)n * 256 + kb * 4) = ph;
    *(uint4*)(wtl + (size_t)n * 256 + kb * 4) = pl;
}

/* ---- gi = x @ w_ih + b_ih on the MATRIX pipe (bf16x3 split) ----
   C = Xh@Wh + Xh@Wl + Xl@Wh (dropped Xl@Wl <= 2^-18 rel).
   Block 256 thr = 4 waves; tile BM=64 x BN=256; BK=32 (16 pairs).
   Wave wv owns cols [wv*64, wv*64+64) = 4 16-col subtiles; 4x4x3 = 48
   MFMA(16x16x32_bf16) per K-step per wave. LDS pair tiles stride 20 u32
   (pad: 16B-aligned b128 reads, ~2-way banks). Operand/C-layout identical
   to k_persist's proven convention: A lane cx=row, B lane cx=col,
   C col=lane&15, row=(lane>>4)*4+reg (m89). */
__global__ __launch_bounds__(256) void k_gi_mfma(const unsigned* __restrict__ xhp,
                                                 const unsigned* __restrict__ xlp,
                                                 const unsigned* __restrict__ wthp,
                                                 const unsigned* __restrict__ wtlp,
                                                 const float* __restrict__ bias,
                                                 float* __restrict__ C,
                                                 int m0g, int M) {
    __shared__ unsigned Au[64 * 20], Al[64 * 20];
    __shared__ unsigned Bu[256 * 20], Bl[256 * 20];
    int tid = threadIdx.x;
    int bm0 = blockIdx.x * 64;
    int n0 = blockIdx.y * 256;
    int wv = tid >> 6, lane = tid & 63;
    int cx = lane & 15, kg = lane >> 4;

    int ar = tid >> 2, aq = (tid & 3) * 4; /* A: 64 rows x 4 segs */
    int rga = bm0 + ar;
    if (rga > M - 1) rga = M - 1; /* clamp (rows >= M recomputed, not stored) */
    const uint4* pah = (const uint4*)(xhp + (size_t)(m0g + rga) * 256 + aq);
    const uint4* pal = (const uint4*)(xlp + (size_t)(m0g + rga) * 256 + aq);

    f32x4 acc[4][4]; /* [m][nn] */
#pragma unroll
    for (int m = 0; m < 4; ++m)
#pragma unroll
        for (int nn = 0; nn < 4; ++nn) acc[m][nn] = (f32x4){0.f, 0.f, 0.f, 0.f};

    for (int kt = 0; kt < 16; ++kt) {
        int po = kt * 4; /* uint4 offset = kt*16 u32 pairs */
        __syncthreads(); /* WAR: previous frag reads done */
        {
            uint4 vh = pah[po], vl = pal[po];
            *(uint4*)&Au[ar * 20 + aq] = vh;
            *(uint4*)&Al[ar * 20 + aq] = vl;
#pragma unroll
            for (int it = 0; it < 4; ++it) {
                int rb = (tid >> 2) + it * 64;
                uint4 bh = *(const uint4*)(wthp + (size_t)(n0 + rb) * 256 + kt * 16 + aq);
                uint4 bl = *(const uint4*)(wtlp + (size_t)(n0 + rb) * 256 + kt * 16 + aq);
                *(uint4*)&Bu[rb * 20 + aq] = bh;
                *(uint4*)&Bl[rb * 20 + aq] = bl;
            }
        }
        __syncthreads();
        short8 ah[4], al4[4], bh4[4], bl4[4];
#pragma unroll
        for (int m = 0; m < 4; ++m) {
            ah[m] = *(const short8*)&Au[(m * 16 + cx) * 20 + kg * 4];
            al4[m] = *(const short8*)&Al[(m * 16 + cx) * 20 + kg * 4];
        }
#pragma unroll
        for (int nn = 0; nn < 4; ++nn) {
            bh4[nn] = *(const short8*)&Bu[(wv * 64 + nn * 16 + cx) * 20 + kg * 4];
            bl4[nn] = *(const short8*)&Bl[(wv * 64 + nn * 16 + cx) * 20 + kg * 4];
        }
#pragma unroll
        for (int m = 0; m < 4; ++m)
#pragma unroll
            for (int nn = 0; nn < 4; ++nn) {
                acc[m][nn] = __builtin_amdgcn_mfma_f32_16x16x32_bf16(ah[m], bh4[nn], acc[m][nn], 0, 0, 0);
                acc[m][nn] = __builtin_amdgcn_mfma_f32_16x16x32_bf16(ah[m], bl4[nn], acc[m][nn], 0, 0, 0);
                acc[m][nn] = __builtin_amdgcn_mfma_f32_16x16x32_bf16(al4[m], bh4[nn], acc[m][nn], 0, 0, 0);
            }
    }
    /* epilogue: C col = cx, row = kg*4 + i */
#pragma unroll
    for (int nn = 0; nn < 4; ++nn) {
        int gcol = n0 + wv * 64 + nn * 16 + cx;
        float bia = bias[gcol];
#pragma unroll
        for (int m = 0; m < 4; ++m) {
            int grow = bm0 + m * 16 + kg * 4;
#pragma unroll
            for (int i = 0; i < 4; ++i)
                if (grow + i < M)
                    C[(size_t)(grow + i) * G3 + gcol] = acc[m][nn][i] + bia;
        }
    }
}

/* ---- f32 fallback gi GEMM (used when ws can't hold split planes) ---- */
__global__ __launch_bounds__(256) void k_gi_gemm(const float* __restrict__ A,
                                                 const float* __restrict__ B,
                                                 const float* __restrict__ bias,
                                                 float* __restrict__ C, int M) {
    __shared__ float As[8][128];
    __shared__ float Bs[8][128];
    int tid = threadIdx.x;
    int m0 = blockIdx.x * 128;
    int n0 = blockIdx.y * 128;
    int tx = tid & 15, ty = tid >> 4;
    int rowA = tid >> 1, kA = (tid & 1) * 4;
    int kB = tid >> 5, cB = (tid & 31) * 4;
    float acc[8][8] = {};
    for (int k0 = 0; k0 < 512; k0 += 8) {
        int rg = m0 + rowA;
        if (rg > M - 1) rg = M - 1;
        float4 a4 = *(const float4*)(A + (size_t)rg * 512 + k0 + kA);
        float4 b4 = *(const float4*)(B + (size_t)(k0 + kB) * G3 + n0 + cB);
        __syncthreads();
        As[kA + 0][rowA] = a4.x;
        As[kA + 1][rowA] = a4.y;
        As[kA + 2][rowA] = a4.z;
        As[kA + 3][rowA] = a4.w;
        *(float4*)&Bs[kB][cB] = b4;
        __syncthreads();
#pragma unroll
        for (int kk = 0; kk < 8; ++kk) {
            float4 a0 = *(const float4*)&As[kk][ty * 8];
            float4 a1 = *(const float4*)&As[kk][ty * 8 + 4];
            float4 b0 = *(const float4*)&Bs[kk][tx * 8];
            float4 b1 = *(const float4*)&Bs[kk][tx * 8 + 4];
            float av[8] = {a0.x, a0.y, a0.z, a0.w, a1.x, a1.y, a1.z, a1.w};
            float bv[8] = {b0.x, b0.y, b0.z, b0.w, b1.x, b1.y, b1.z, b1.w};
#pragma unroll
            for (int i = 0; i < 8; ++i)
#pragma unroll
                for (int j = 0; j < 8; ++j) acc[i][j] += av[i] * bv[j];
        }
    }
    float4 bi0 = *(const float4*)(bias + n0 + tx * 8);
    float4 bi1 = *(const float4*)(bias + n0 + tx * 8 + 4);
    float bb[8] = {bi0.x, bi0.y, bi0.z, bi0.w, bi1.x, bi1.y, bi1.z, bi1.w};
#pragma unroll
    for (int i = 0; i < 8; ++i) {
        int row = m0 + ty * 8 + i;
        if (row < M) {
            float4 s0 = {acc[i][0] + bb[0], acc[i][1] + bb[1], acc[i][2] + bb[2], acc[i][3] + bb[3]};
            float4 s1 = {acc[i][4] + bb[4], acc[i][5] + bb[5], acc[i][6] + bb[6], acc[i][7] + bb[7]};
            *(float4*)(C + (size_t)row * G3 + n0 + tx * 8) = s0;
            *(float4*)(C + (size_t)row * G3 + n0 + tx * 8 + 4) = s1;
        }
    }
}

/* ---- persistent recurrent kernel, v9 = v5/v8 + part DOUBLE-BUFFER ----
   ONE isolated change vs the proven v8 kernel: part[2] and NO loop-end
   barrier. Effect: after barrier(s) (which sits BEFORE gates), waves 2-7
   flow straight into poll(s+1) while waves 0-1 run the gates tail
   (reduce+gate-math+bsplit+stores, ~500cy) -> the tail overlaps the next
   poll wait instead of gating it. Safety: gates(s) reads part[s&1]; the
   earliest rewrite of that buffer is MFMA(s+2), which is after
   barrier(s+1), which waves 0-1 reach only after gates(s) completes in
   program order. Max inter-wave skew = 1 step. All global-memory
   behavior is byte-identical to v8 (falsifiable signature: WRITE_SIZE
   stays 196MB, bank conflicts stay 1.26e7 — v6's regressions came from
   its OTHER two changes, which are not reintroduced). */
__global__ __launch_bounds__(512, 2) void k_persist(const float* __restrict__ w_hh,
                                                    const float* __restrict__ gi,
                                                    const float* __restrict__ pad,
                                                    const float* __restrict__ b_hh,
                                                    float* __restrict__ out,
                                                    unsigned long long* __restrict__ hstage,
                                                    int t0, int ct) {
    __shared__ float part[2][4608]; /* [par][wave*576 + g*192 + col*12 + b] */

    int tid = threadIdx.x;
    int hg = blockIdx.x & 63, boct = blockIdx.x >> 6;
    int hc0 = hg << 4;
    int b0 = boct << 3;

    int wk = tid >> 6;  /* wave id = k-slice [wk*128, wk*128+128) */
    int lane = tid & 63;
    int kg = lane >> 4; /* k-group within frag */
    int cx = lane & 15; /* A-row (batch) / C-col */

    /* ---- one-time: weights -> bf16 hi/lo frags in VGPRs (96 regs) ---- */
    short8 Bh[3][4], Bl[3][4];
#pragma unroll
    for (int g = 0; g < 3; ++g)
#pragma unroll
        for (int kf = 0; kf < 4; ++kf) {
            unsigned hh_[8], ll_[8];
#pragma unroll
            for (int j = 0; j < 8; ++j) {
                int k = wk * 128 + kf * 32 + kg * 8 + j;
                float w = w_hh[(size_t)k * G3 + hc0 + cx + g * HH];
                bsplit(w, hh_[j], ll_[j]);
            }
            union { unsigned u[4]; short8 s; } ph, pl;
#pragma unroll
            for (int r = 0; r < 4; ++r) {
                ph.u[r] = hh_[2 * r] | (hh_[2 * r + 1] << 16);
                pl.u[r] = ll_[2 * r] | (ll_[2 * r + 1] << 16);
            }
            Bh[g][kf] = ph.s;
            Bl[g][kf] = pl.s;
        }

    /* gate-thread constants (tid<128: col = hc0+cg, batch = b2) */
    int cg = tid & 15, b2 = tid >> 4;
    int col = hc0 + cg;
    int bg = b0 + b2;
    float bhr = 0.f, bhz = 0.f, bhn = 0.f, hprev = 0.f;
    if (tid < 128) {
        bhr = b_hh[col];
        bhz = b_hh[col + HH];
        bhn = b_hh[col + 2 * HH];
        if (t0 > 0) /* chunk resume: prev dispatch's h, flushed+visible */
            hprev = out[(size_t)(t0 - 1) * (BB * HH) + (size_t)bg * HH + col];
    }

    /* producer staging address: col -> (kf,j,kg) slot in frag order */
    int co = ((hg & 7) << 4) | cg; /* k-offset within my wk-slice, 0..127 */
    size_t sbase_p = (size_t)boct * 2097152 + (size_t)(hg >> 3) * 512 +
                     (size_t)((co >> 5) * 64 + ((co >> 2) & 1) * 32 +
                              ((co >> 3) & 3) * 8 + b2);
    /* consumer base: lane (kg,cx<8) reads 16 u64s at +plane*256+kf*64+j*32 */
    size_t cbase = (size_t)boct * 2097152 + (size_t)wk * 512 + (size_t)(kg * 8 + cx);

    for (int s = 0; s < ct; ++s) {
        int t = t0 + s;
        int par = s & 1;

        /* prefetch gi + pad (plain loads, consumed in gates phase) */
        float gir = 0.f, giz = 0.f, gin = 0.f, pv = 0.f;
        if (tid < 128) {
            const float* gp = gi + ((size_t)s * BB + bg) * G3 + col;
            gir = gp[0];
            giz = gp[HH];
            gin = gp[2 * HH];
            pv = pad[t * BB + bg];
        }

        /* ---- A-frags: poll-load packed staging of h(t-1) ---- */
        unsigned long long v[16];
        if (t > 0 && cx < 8) {
            const unsigned long long* sp = hstage + cbase + (size_t)(t - 1) * 4096;
#pragma unroll
            for (int i = 0; i < 16; ++i)
                v[i] = __hip_atomic_load(sp + (i >> 3) * 256 + ((i >> 1) & 3) * 64 +
                                             (i & 1) * 32,
                                         __ATOMIC_RELAXED, __HIP_MEMORY_SCOPE_AGENT);
            for (;;) {
                int bad = 0;
#pragma unroll
                for (int i = 0; i < 16; ++i)
                    if ((unsigned)v[i] == 0xFFFFFFFFu ||
                        (unsigned)(v[i] >> 32) == 0xFFFFFFFFu)
                        bad |= 1 << i;
                if (!bad) break;
#pragma unroll
                for (int i = 0; i < 16; ++i)
                    if (bad & (1 << i))
                        v[i] = __hip_atomic_load(sp + (i >> 3) * 256 +
                                                     ((i >> 1) & 3) * 64 + (i & 1) * 32,
                                                 __ATOMIC_RELAXED,
                                                 __HIP_MEMORY_SCOPE_AGENT);
            }
        } else {
#pragma unroll
            for (int i = 0; i < 16; ++i) v[i] = 0ull;
        }

        /* MFMA: 4 k-frags x 3 gates x 3 (bf16x3) = 36 per wave */
        f32x4 acc[3];
        acc[0] = (f32x4){0.f, 0.f, 0.f, 0.f};
        acc[1] = (f32x4){0.f, 0.f, 0.f, 0.f};
        acc[2] = (f32x4){0.f, 0.f, 0.f, 0.f};
#pragma unroll
        for (int kf = 0; kf < 4; ++kf) {
            union { unsigned long long q[2]; short8 s8; } uh, ul;
            uh.q[0] = v[kf * 2];
            uh.q[1] = v[kf * 2 + 1];
            ul.q[0] = v[8 + kf * 2];
            ul.q[1] = v[8 + kf * 2 + 1];
#pragma unroll
            for (int g = 0; g < 3; ++g) {
                acc[g] = __builtin_amdgcn_mfma_f32_16x16x32_bf16(uh.s8, Bh[g][kf], acc[g], 0, 0, 0);
                acc[g] = __builtin_amdgcn_mfma_f32_16x16x32_bf16(uh.s8, Bl[g][kf], acc[g], 0, 0, 0);
                acc[g] = __builtin_amdgcn_mfma_f32_16x16x32_bf16(ul.s8, Bh[g][kf], acc[g], 0, 0, 0);
            }
        }
        /* partial C: lanes 0..31 hold valid batch rows 0..7 */
        if (lane < 32) {
            int r0 = (lane >> 4) * 4;
#pragma unroll
            for (int g = 0; g < 3; ++g)
                *(f32x4*)&part[par][wk * 576 + g * 192 + cx * 12 + r0] = acc[g];
        }
        __syncthreads(); /* part[par] complete; the ONLY barrier per step */

        /* gates: 128 threads reduce 8 wave-partials per (g,b,col);
           waves 2-7 skip this and flow straight into poll(s+1) */
        if (tid < 128) {
            float gh0 = 0.f, gh1 = 0.f, gh2 = 0.f;
#pragma unroll
            for (int w = 0; w < 8; ++w) {
                int base = w * 576 + cg * 12 + b2;
                gh0 += part[par][base];
                gh1 += part[par][base + 192];
                gh2 += part[par][base + 384];
            }
            float r = sigmoidf_(gir + gh0 + bhr);
            float z = sigmoidf_(giz + gh1 + bhz);
            float n = tanh_fast(gin + r * (gh2 + bhn));
            float hnew = (1.f - z) * n + z * hprev;
            hnew = pv * hprev + (1.f - pv) * hnew;
            hprev = hnew; /* exact f32 carried to next step */

            /* ---- stage FIRST: split, pair-pack via 4-lane shuffles ---- */
            unsigned hi_, lo_;
            bsplit(hnew, hi_, lo_);
            unsigned hiA = hi_ | (((unsigned)__shfl_xor((int)hi_, 1)) << 16);
            unsigned loA = lo_ | (((unsigned)__shfl_xor((int)lo_, 1)) << 16);
            unsigned hiB = (unsigned)__shfl_xor((int)hiA, 2);
            unsigned loB = (unsigned)__shfl_xor((int)loA, 2);
            if ((cg & 3) == 0) {
                unsigned long long hq =
                    (unsigned long long)hiA | ((unsigned long long)hiB << 32);
                unsigned long long lq =
                    (unsigned long long)loA | ((unsigned long long)loB << 32);
                unsigned long long* dst = hstage + sbase_p + (size_t)t * 4096;
                __hip_atomic_store(dst, hq, __ATOMIC_RELAXED,
                                   __HIP_MEMORY_SCOPE_AGENT);
                __hip_atomic_store(dst + 256, lq, __ATOMIC_RELAXED,
                                   __HIP_MEMORY_SCOPE_AGENT);
            }
            size_t oo = (size_t)t * (BB * HH) + (size_t)bg * HH + col;
            out[oo] = hnew;
            out[(size_t)TBH + oo] = hnew;
        }
        /* no loop-end barrier: part is double-buffered (see header) */
    }
}

/* ---- emergency fallback if workspace is tiny: fused, slow, correct ---- */
__global__ __launch_bounds__(256) void k_step_slow(const float* __restrict__ x_t,
                                                   const float* __restrict__ pad_t,
                                                   const float* __restrict__ w_ih,
                                                   const float* __restrict__ w_hh,
                                                   const float* __restrict__ b_ih,
                                                   const float* __restrict__ b_hh,
                                                   const float* __restrict__ h_in,
                                                   float* __restrict__ h_out,
                                                   float* __restrict__ out, int t) {
    int g = blockIdx.x * 256 + threadIdx.x;
    int b = g >> 10, j = g & 1023;
    float gir = b_ih[j], giz = b_ih[j + HH], gin = b_ih[j + 2 * HH];
    for (int k = 0; k < II; ++k) {
        float xv = x_t[b * II + k];
        const float* wr = w_ih + (size_t)k * G3;
        gir += xv * wr[j];
        giz += xv * wr[j + HH];
        gin += xv * wr[j + 2 * HH];
    }
    float ghr = b_hh[j], ghz = b_hh[j + HH], ghn = b_hh[j + 2 * HH];
    for (int k = 0; k < HH; ++k) {
        float hv = h_in[b * HH + k];
        const float* wr = w_hh + (size_t)k * G3;
        ghr += hv * wr[j];
        ghz += hv * wr[j + HH];
        ghn += hv * wr[j + 2 * HH];
    }
    float hprev = h_in[b * HH + j];
    float p = pad_t[b];
    float r = sigmoidf_(gir + ghr);
    float z = sigmoidf_(giz + ghz);
    float n = tanh_fast(gin + r * ghn);
    float hnew = (1.f - z) * n + z * hprev;
    hnew = p * hprev + (1.f - p) * hnew;
    size_t o = (size_t)b * HH + j;
    h_out[o] = hnew;
    size_t oo = (size_t)t * (BB * HH) + o;
    out[oo] = hnew;
    out[(size_t)TBH + oo] = hnew;
}

extern "C" void kernel_launch(void* const* d_in, const int* in_sizes, int n_in,
                              void* d_out, int out_size, void* d_ws, size_t ws_size,
                              hipStream_t stream) {
    const float* x    = (const float*)d_in[0];
    const float* pad  = (const float*)d_in[1];
    const float* w_ih = (const float*)d_in[2];
    const float* w_hh = (const float*)d_in[3];
    const float* b_ih = (const float*)d_in[4];
    const float* b_hh = (const float*)d_in[5];
    float* out = (float*)d_out;

    char* wsb = (char*)d_ws;
    float* hA = (float*)wsb;            /* 128 KB (fallback only) */
    float* hB = (float*)(wsb + 131072); /* 128 KB (fallback only) */
    unsigned long long* hstage = (unsigned long long*)(wsb + 262144); /* 64 MB */
    /* split-plane layout (preferred path) */
    unsigned* xh  = (unsigned*)(wsb + 67371008);  /* 16 MB: [16384][256] pairs */
    unsigned* xl  = (unsigned*)(wsb + 84148224);  /* 16 MB */
    unsigned* wth = (unsigned*)(wsb + 100925440); /* 3 MB: [3072][256] pairs */
    unsigned* wtl = (unsigned*)(wsb + 104071168); /* 3 MB */
    float* gi_new = (float*)(wsb + 107216896);
    float* gi_old = (float*)(wsb + 67371008);

    long long cap_new = (long long)ws_size - 107216896LL;
    long long cap_old = (long long)ws_size - 67371008LL;
    int Tc_new = cap_new > 0 ? (int)(cap_new / 393216LL) : 0;
    int Tc_old = cap_old > 0 ? (int)(cap_old / 393216LL) : 0;
    if (Tc_new > TT) Tc_new = TT;
    if (Tc_old > TT) Tc_old = TT;

    if (Tc_new >= 1) {
        /* MFMA gi path: pre-split x and w_ih once */
        k_split_x<<<4096, 256, 0, stream>>>(x, xh, xl);
        k_split_w<<<768, 256, 0, stream>>>(w_ih, wth, wtl);
        hipMemsetAsync(hstage, 0xFF, 67108864, stream); /* bf16 NaN sentinel */
        for (int t0 = 0; t0 < TT; t0 += Tc_new) {
            int ctn = (TT - t0 < Tc_new) ? (TT - t0) : Tc_new;
            int M = ctn * BB;
            dim3 g((M + 63) / 64, 12);
            k_gi_mfma<<<g, 256, 0, stream>>>(xh, xl, wth, wtl, b_ih, gi_new,
                                             t0 * BB, M);
            k_persist<<<256, 512, 0, stream>>>(w_hh, gi_new, pad, b_hh, out,
                                               hstage, t0, ctn);
        }
    } else if (Tc_old >= 1) {
        hipMemsetAsync(hstage, 0xFF, 67108864, stream);
        for (int t0 = 0; t0 < TT; t0 += Tc_old) {
            int ctn = (TT - t0 < Tc_old) ? (TT - t0) : Tc_old;
            int M = ctn * BB;
            dim3 g((M + 127) / 128, 24);
            k_gi_gemm<<<g, 256, 0, stream>>>(x + (size_t)t0 * BB * II, w_ih, b_ih,
                                             gi_old, M);
            k_persist<<<256, 512, 0, stream>>>(w_hh, gi_old, pad, b_hh, out,
                                               hstage, t0, ctn);
        }
    } else {
        hipMemsetAsync(hA, 0, 131072, stream); /* h(t=0) = 0 */
        for (int t = 0; t < TT; ++t) {
            const float* hin = (t & 1) ? hB : hA;
            float* hout = (t & 1) ? hA : hB;
            k_step_slow<<<128, 256, 0, stream>>>(x + (size_t)t * BB * II, pad + t * BB,
                                                 w_ih, w_hh, b_ih, b_hh, hin, hout, out, t);
        }
    }
}

// Round 10
// 1728.560 us; speedup vs baseline: 1.4814x; 1.4814x over previous
//
#include <hip/hip_runtime.h>

#define TT 512
#define BB 32
#define II 512
#define HH 1024
#define G3 3072
#define TBH (TT * BB * HH) /* 16777216 */

typedef __attribute__((ext_vector_type(8))) short short8;
typedef __attribute__((ext_vector_type(4))) float f32x4;

__device__ __forceinline__ float sigmoidf_(float x) {
    return 1.f / (1.f + __expf(-x));
}
__device__ __forceinline__ float tanh_fast(float x) {
    float e2 = __expf(2.f * x);
    return 1.f - 2.f / (e2 + 1.f);
}
/* round-to-nearest-even f32 -> bf16 (top 16 bits) */
__device__ __forceinline__ unsigned rne16(float x) {
    unsigned u = __float_as_uint(x);
    return (u + 0x7FFFu + ((u >> 16) & 1u)) >> 16;
}
/* split x = hi + lo (both bf16); |x - hi - lo| <= ~2^-18 |x|.
   For finite x, neither hi nor lo can be 0xFFFF (bf16 NaN) -> sentinel-safe. */
__device__ __forceinline__ void bsplit(float x, unsigned& hi, unsigned& lo) {
    unsigned h16 = rne16(x);
    float xh = __uint_as_float(h16 << 16);
    hi = h16;
    lo = rne16(x - xh); /* x - xh is exact */
}

/* ---- pre-split x into MFMA-frag-ordered bf16 hi/lo u64 planes ----
   xsplit u64 layout: [t 512][oct 4][wk 8]{ hi[128] | lo[128] } where the
   128 within-plane index = kf*64 + j*32 + kg*8 + cx, holding 4 bf16 of
   x[t][oct*8+cx][wk*64 + kf*32 + kg*8 + j*4 .. +3]. Matches k_persist's
   A-frag read: lane (kg,cx) reads (kf,j=0,1) pairs = 8 bf16 in k-order. */
__global__ __launch_bounds__(256) void k_split_x(const float* __restrict__ x,
                                                 unsigned long long* __restrict__ xsplit) {
    int g = blockIdx.x * 256 + threadIdx.x; /* 2,097,152 = 512t x 32b x 128q */
    int t = g >> 12;
    int r = g & 4095;
    int b = r >> 7, q = r & 127;
    float4 s = *(const float4*)(x + ((size_t)t * 32 + b) * 512 + q * 4);
    unsigned h0, l0, h1, l1, h2, l2, h3, l3;
    bsplit(s.x, h0, l0);
    bsplit(s.y, h1, l1);
    bsplit(s.z, h2, l2);
    bsplit(s.w, h3, l3);
    unsigned long long hq = (unsigned long long)(h0 | (h1 << 16)) |
                            ((unsigned long long)(h2 | (h3 << 16)) << 32);
    unsigned long long lq = (unsigned long long)(l0 | (l1 << 16)) |
                            ((unsigned long long)(l2 | (l3 << 16)) << 32);
    int oct = b >> 3, cx = b & 7;
    int wk = q >> 4, kf = (q >> 3) & 1, kg = (q >> 1) & 3, j = q & 1;
    size_t base = (((size_t)t * 4 + oct) * 8 + wk) * 256;
    size_t w_ = (size_t)(kf * 64 + j * 32 + kg * 8 + cx);
    xsplit[base + w_] = hq;
    xsplit[base + 128 + w_] = lq;
}

/* ---- persistent recurrent kernel, v10 = v8 sync structure + fused gi ----
   grid 256 = 64 h-col-groups x 4 batch-octets; block 512 thr = 8 waves.
   EXACT v8/v5 exchange (R9 proved the loop-end barrier is a poll
   rate-limiter: removing it made early polls miss L3 and fetch sentinel
   lines from HBM, +210MB FETCH, +30% dur. Do not touch the 2-barrier
   step or poll placement.)
   NEW: gi = x@W_ih computed IN-KERNEL on the idle matrix pipe. Per wave
   per step: +18 MFMA (2 kf x 3 gates x bf16x3) on pre-split x frags
   (8 plain u64 loads, always ready) + W_ih frags in 48 VGPRs (one-time).
   The n-gate needs x/h parts separate (n = tanh(i_n + r*h_n)), so acc has
   4 planes: 0=r(x+h), 1=z(x+h), 2=n_x, 3=n_h; part = [wk][4g][16cx][12].
   Removes the separate gi GEMM kernel and its 192MB buffer traffic. */
__global__ __launch_bounds__(512, 2) void k_persist(const float* __restrict__ w_hh,
                                                    const float* __restrict__ w_ih,
                                                    const float* __restrict__ pad,
                                                    const float* __restrict__ b_ih,
                                                    const float* __restrict__ b_hh,
                                                    float* __restrict__ out,
                                                    unsigned long long* __restrict__ hstage,
                                                    const unsigned long long* __restrict__ xsplit,
                                                    int t0, int ct) {
    __shared__ float part[8 * 768]; /* [wave][g*192 + col*12 + b] , g=0..3 */

    int tid = threadIdx.x;
    int hg = blockIdx.x & 63, boct = blockIdx.x >> 6;
    int hc0 = hg << 4;
    int b0 = boct << 3;

    int wk = tid >> 6;  /* wave id: h k-slice [wk*128,+128), x k-slice [wk*64,+64) */
    int lane = tid & 63;
    int kg = lane >> 4; /* k-group within frag */
    int cx = lane & 15; /* A-row (batch) / C-col */

    /* ---- one-time: W_hh -> bf16 hi/lo frags (96 VGPRs) ---- */
    short8 Bh[3][4], Bl[3][4];
#pragma unroll
    for (int g = 0; g < 3; ++g)
#pragma unroll
        for (int kf = 0; kf < 4; ++kf) {
            unsigned hh_[8], ll_[8];
#pragma unroll
            for (int j = 0; j < 8; ++j) {
                int k = wk * 128 + kf * 32 + kg * 8 + j;
                float w = w_hh[(size_t)k * G3 + hc0 + cx + g * HH];
                bsplit(w, hh_[j], ll_[j]);
            }
            union { unsigned u[4]; short8 s; } ph, pl;
#pragma unroll
            for (int r = 0; r < 4; ++r) {
                ph.u[r] = hh_[2 * r] | (hh_[2 * r + 1] << 16);
                pl.u[r] = ll_[2 * r] | (ll_[2 * r + 1] << 16);
            }
            Bh[g][kf] = ph.s;
            Bl[g][kf] = pl.s;
        }
    /* ---- one-time: W_ih -> bf16 hi/lo frags (48 VGPRs) ---- */
    short8 Ih[3][2], Il[3][2];
#pragma unroll
    for (int g = 0; g < 3; ++g)
#pragma unroll
        for (int kf = 0; kf < 2; ++kf) {
            unsigned hh_[8], ll_[8];
#pragma unroll
            for (int j = 0; j < 8; ++j) {
                int k = wk * 64 + kf * 32 + kg * 8 + j;
                float w = w_ih[(size_t)k * G3 + hc0 + cx + g * HH];
                bsplit(w, hh_[j], ll_[j]);
            }
            union { unsigned u[4]; short8 s; } ph, pl;
#pragma unroll
            for (int r = 0; r < 4; ++r) {
                ph.u[r] = hh_[2 * r] | (hh_[2 * r + 1] << 16);
                pl.u[r] = ll_[2 * r] | (ll_[2 * r + 1] << 16);
            }
            Ih[g][kf] = ph.s;
            Il[g][kf] = pl.s;
        }

    /* gate-thread constants (tid<128: col = hc0+cg, batch = b2) */
    int cg = tid & 15, b2 = tid >> 4;
    int col = hc0 + cg;
    int bg = b0 + b2;
    float cR = 0.f, cZ = 0.f, bin = 0.f, bhn = 0.f, hprev = 0.f;
    if (tid < 128) {
        cR = b_ih[col] + b_hh[col];
        cZ = b_ih[col + HH] + b_hh[col + HH];
        bin = b_ih[col + 2 * HH];
        bhn = b_hh[col + 2 * HH];
        if (t0 > 0)
            hprev = out[(size_t)(t0 - 1) * (BB * HH) + (size_t)bg * HH + col];
    }

    /* producer staging address: col -> (kf,j,kg) slot in frag order */
    int co = ((hg & 7) << 4) | cg; /* k-offset within my wk-slice, 0..127 */
    size_t sbase_p = (size_t)boct * 2097152 + (size_t)(hg >> 3) * 512 +
                     (size_t)((co >> 5) * 64 + ((co >> 2) & 1) * 32 +
                              ((co >> 3) & 3) * 8 + b2);
    /* consumer base: lane (kg,cx<8) reads 16 u64s at +plane*256+kf*64+j*32 */
    size_t cbase = (size_t)boct * 2097152 + (size_t)wk * 512 + (size_t)(kg * 8 + cx);

    for (int s = 0; s < ct; ++s) {
        int t = t0 + s;

        /* pad prefetch */
        float pv = 0.f;
        if (tid < 128) pv = pad[t * BB + bg];

        /* ---- x A-frags: plain loads from pre-split planes (no polling);
           issued BEFORE the poll so they complete under the spin ---- */
        unsigned long long xv[8];
        if (cx < 8) {
            const unsigned long long* xp =
                xsplit + ((((size_t)t * 4 + boct) * 8 + wk) << 8);
            int off = kg * 8 + cx;
#pragma unroll
            for (int kf = 0; kf < 2; ++kf)
#pragma unroll
                for (int j = 0; j < 2; ++j) {
                    xv[kf * 2 + j] = xp[kf * 64 + j * 32 + off];
                    xv[4 + kf * 2 + j] = xp[128 + kf * 64 + j * 32 + off];
                }
        } else {
#pragma unroll
            for (int i = 0; i < 8; ++i) xv[i] = 0ull;
        }

        /* ---- h A-frags: poll-load packed staging of h(t-1) ---- */
        unsigned long long v[16];
        if (t > 0 && cx < 8) {
            const unsigned long long* sp = hstage + cbase + (size_t)(t - 1) * 4096;
#pragma unroll
            for (int i = 0; i < 16; ++i)
                v[i] = __hip_atomic_load(sp + (i >> 3) * 256 + ((i >> 1) & 3) * 64 +
                                             (i & 1) * 32,
                                         __ATOMIC_RELAXED, __HIP_MEMORY_SCOPE_AGENT);
            for (;;) {
                int bad = 0;
#pragma unroll
                for (int i = 0; i < 16; ++i)
                    if ((unsigned)v[i] == 0xFFFFFFFFu ||
                        (unsigned)(v[i] >> 32) == 0xFFFFFFFFu)
                        bad |= 1 << i;
                if (!bad) break;
#pragma unroll
                for (int i = 0; i < 16; ++i)
                    if (bad & (1 << i))
                        v[i] = __hip_atomic_load(sp + (i >> 3) * 256 +
                                                     ((i >> 1) & 3) * 64 + (i & 1) * 32,
                                                 __ATOMIC_RELAXED,
                                                 __HIP_MEMORY_SCOPE_AGENT);
            }
        } else {
#pragma unroll
            for (int i = 0; i < 16; ++i) v[i] = 0ull;
        }

        /* MFMA: acc planes 0=r(x+h), 1=z(x+h), 2=n_x, 3=n_h */
        f32x4 acc[4];
        acc[0] = (f32x4){0.f, 0.f, 0.f, 0.f};
        acc[1] = (f32x4){0.f, 0.f, 0.f, 0.f};
        acc[2] = (f32x4){0.f, 0.f, 0.f, 0.f};
        acc[3] = (f32x4){0.f, 0.f, 0.f, 0.f};
        /* x part: 2 kf x 3 gates x 3 = 18 MFMA */
#pragma unroll
        for (int kf = 0; kf < 2; ++kf) {
            union { unsigned long long q[2]; short8 s8; } uh, ul;
            uh.q[0] = xv[kf * 2];
            uh.q[1] = xv[kf * 2 + 1];
            ul.q[0] = xv[4 + kf * 2];
            ul.q[1] = xv[4 + kf * 2 + 1];
#pragma unroll
            for (int g = 0; g < 3; ++g) {
                int tg = g; /* gate 2 (n) x-part -> acc[2] */
                acc[tg] = __builtin_amdgcn_mfma_f32_16x16x32_bf16(uh.s8, Ih[g][kf], acc[tg], 0, 0, 0);
                acc[tg] = __builtin_amdgcn_mfma_f32_16x16x32_bf16(uh.s8, Il[g][kf], acc[tg], 0, 0, 0);
                acc[tg] = __builtin_amdgcn_mfma_f32_16x16x32_bf16(ul.s8, Ih[g][kf], acc[tg], 0, 0, 0);
            }
        }
        /* h part: 4 kf x 3 gates x 3 = 36 MFMA */
#pragma unroll
        for (int kf = 0; kf < 4; ++kf) {
            union { unsigned long long q[2]; short8 s8; } uh, ul;
            uh.q[0] = v[kf * 2];
            uh.q[1] = v[kf * 2 + 1];
            ul.q[0] = v[8 + kf * 2];
            ul.q[1] = v[8 + kf * 2 + 1];
#pragma unroll
            for (int g = 0; g < 3; ++g) {
                int tg = (g == 2) ? 3 : g; /* gate 2 (n) h-part -> acc[3] */
                acc[tg] = __builtin_amdgcn_mfma_f32_16x16x32_bf16(uh.s8, Bh[g][kf], acc[tg], 0, 0, 0);
                acc[tg] = __builtin_amdgcn_mfma_f32_16x16x32_bf16(uh.s8, Bl[g][kf], acc[tg], 0, 0, 0);
                acc[tg] = __builtin_amdgcn_mfma_f32_16x16x32_bf16(ul.s8, Bh[g][kf], acc[tg], 0, 0, 0);
            }
        }
        /* partial C: lanes 0..31 hold valid batch rows 0..7 */
        if (lane < 32) {
            int r0 = (lane >> 4) * 4;
#pragma unroll
            for (int g = 0; g < 4; ++g)
                *(f32x4*)&part[wk * 768 + g * 192 + cx * 12 + r0] = acc[g];
        }
        __syncthreads();

        /* gates: 128 threads reduce 8 wave-partials per (g,b,col) */
        if (tid < 128) {
            float gh0 = 0.f, gh1 = 0.f, gh2 = 0.f, gh3 = 0.f;
#pragma unroll
            for (int w = 0; w < 8; ++w) {
                int base = w * 768 + cg * 12 + b2;
                gh0 += part[base];
                gh1 += part[base + 192];
                gh2 += part[base + 384];
                gh3 += part[base + 576];
            }
            float r = sigmoidf_(gh0 + cR);
            float z = sigmoidf_(gh1 + cZ);
            float n = tanh_fast(gh2 + bin + r * (gh3 + bhn));
            float hnew = (1.f - z) * n + z * hprev;
            hnew = pv * hprev + (1.f - pv) * hnew;
            hprev = hnew; /* exact f32 carried to next step */

            /* stage FIRST: split, pair-pack via 4-lane shuffles */
            unsigned hi_, lo_;
            bsplit(hnew, hi_, lo_);
            unsigned hiA = hi_ | (((unsigned)__shfl_xor((int)hi_, 1)) << 16);
            unsigned loA = lo_ | (((unsigned)__shfl_xor((int)lo_, 1)) << 16);
            unsigned hiB = (unsigned)__shfl_xor((int)hiA, 2);
            unsigned loB = (unsigned)__shfl_xor((int)loA, 2);
            if ((cg & 3) == 0) {
                unsigned long long hq =
                    (unsigned long long)hiA | ((unsigned long long)hiB << 32);
                unsigned long long lq =
                    (unsigned long long)loA | ((unsigned long long)loB << 32);
                unsigned long long* dst = hstage + sbase_p + (size_t)t * 4096;
                __hip_atomic_store(dst, hq, __ATOMIC_RELAXED,
                                   __HIP_MEMORY_SCOPE_AGENT);
                __hip_atomic_store(dst + 256, lq, __ATOMIC_RELAXED,
                                   __HIP_MEMORY_SCOPE_AGENT);
            }
            size_t oo = (size_t)t * (BB * HH) + (size_t)bg * HH + col;
            out[oo] = hnew;
            out[(size_t)TBH + oo] = hnew;
        }
        /* WAR guard + poll rate-limiter (R9: do NOT remove) */
        __syncthreads();
    }
}

/* ---- emergency fallback if workspace is tiny: fused, slow, correct ---- */
__global__ __launch_bounds__(256) void k_step_slow(const float* __restrict__ x_t,
                                                   const float* __restrict__ pad_t,
                                                   const float* __restrict__ w_ih,
                                                   const float* __restrict__ w_hh,
                                                   const float* __restrict__ b_ih,
                                                   const float* __restrict__ b_hh,
                                                   const float* __restrict__ h_in,
                                                   float* __restrict__ h_out,
                                                   float* __restrict__ out, int t) {
    int g = blockIdx.x * 256 + threadIdx.x;
    int b = g >> 10, j = g & 1023;
    float gir = b_ih[j], giz = b_ih[j + HH], gin = b_ih[j + 2 * HH];
    for (int k = 0; k < II; ++k) {
        float xv = x_t[b * II + k];
        const float* wr = w_ih + (size_t)k * G3;
        gir += xv * wr[j];
        giz += xv * wr[j + HH];
        gin += xv * wr[j + 2 * HH];
    }
    float ghr = b_hh[j], ghz = b_hh[j + HH], ghn = b_hh[j + 2 * HH];
    for (int k = 0; k < HH; ++k) {
        float hv = h_in[b * HH + k];
        const float* wr = w_hh + (size_t)k * G3;
        ghr += hv * wr[j];
        ghz += hv * wr[j + HH];
        ghn += hv * wr[j + 2 * HH];
    }
    float hprev = h_in[b * HH + j];
    float p = pad_t[b];
    float r = sigmoidf_(gir + ghr);
    float z = sigmoidf_(giz + ghz);
    float n = tanh_fast(gin + r * ghn);
    float hnew = (1.f - z) * n + z * hprev;
    hnew = p * hprev + (1.f - p) * hnew;
    size_t o = (size_t)b * HH + j;
    h_out[o] = hnew;
    size_t oo = (size_t)t * (BB * HH) + o;
    out[oo] = hnew;
    out[(size_t)TBH + oo] = hnew;
}

extern "C" void kernel_launch(void* const* d_in, const int* in_sizes, int n_in,
                              void* d_out, int out_size, void* d_ws, size_t ws_size,
                              hipStream_t stream) {
    const float* x    = (const float*)d_in[0];
    const float* pad  = (const float*)d_in[1];
    const float* w_ih = (const float*)d_in[2];
    const float* w_hh = (const float*)d_in[3];
    const float* b_ih = (const float*)d_in[4];
    const float* b_hh = (const float*)d_in[5];
    float* out = (float*)d_out;

    char* wsb = (char*)d_ws;
    float* hA = (float*)wsb;            /* 128 KB (fallback only) */
    float* hB = (float*)(wsb + 131072); /* 128 KB (fallback only) */
    unsigned long long* hstage = (unsigned long long*)(wsb + 262144);   /* 64 MB */
    unsigned long long* xsplit = (unsigned long long*)(wsb + 67371008); /* 33.5 MB */
    /* end of xsplit = 67371008 + 33554432 = 100925440 */

    if (ws_size >= 100925440ULL) {
        k_split_x<<<8192, 256, 0, stream>>>(x, xsplit);
        hipMemsetAsync(hstage, 0xFF, 67108864, stream); /* bf16 NaN sentinel */
        k_persist<<<256, 512, 0, stream>>>(w_hh, w_ih, pad, b_ih, b_hh, out,
                                           hstage, xsplit, 0, TT);
    } else {
        hipMemsetAsync(hA, 0, 131072, stream); /* h(t=0) = 0 */
        for (int t = 0; t < TT; ++t) {
            const float* hin = (t & 1) ? hB : hA;
            float* hout = (t & 1) ? hA : hB;
            k_step_slow<<<128, 256, 0, stream>>>(x + (size_t)t * BB * II, pad + t * BB,
                                                 w_ih, w_hh, b_ih, b_hh, hin, hout, out, t);
        }
    }
}